// Round 13
// baseline (623.540 us; speedup 1.0000x reference)
//
#include <hip/hip_runtime.h>
#include <hip/hip_bf16.h>
#include <float.h>
#include <math.h>

#define NN 30000
#define NE 70000
#define NG 1024
#define NT 5
#define FI 75
#define NL 4

// AVG_DEG_LOG = (100*ln2 + 400*ln3 + 300*ln4 + 50*ln5)/850
#define AMP_DENOM 1.1824939264481302f

// ABH: [NN][832] bf16 : cols 0..374 = A (h@Wdst), 375..749 = B (h@Wsrc),
//                        750..824 = hterm, 825..831 pad
#define ABW 832
// AGG: [NN][1600] bf16 : per tower t: 320 = 4 stats x 76 (75+pad) + 16 k-pad, pads zero
#define AGW 1600
// hb: [NN][96] bf16, cols 75..95 zero
#define HBW 96
// z: [NN][76] f32
#define ZW 76

typedef __attribute__((ext_vector_type(8))) short bf16x8;
typedef __attribute__((ext_vector_type(4))) float f32x4;

__device__ __forceinline__ float bf2f(unsigned short u) {
    return __uint_as_float(((unsigned int)u) << 16);
}
__device__ __forceinline__ unsigned short f2bf(float f) {
    __hip_bfloat16 h = __float2bfloat16(f);
    return *reinterpret_cast<unsigned short*>(&h);
}

// ---------------- CSR build ----------------
__global__ __launch_bounds__(256) void k_deg(const int* __restrict__ dst, int* __restrict__ deg) {
    int e = blockIdx.x * 256 + threadIdx.x;
    if (e < NE) atomicAdd(&deg[dst[e]], 1);
}

__global__ __launch_bounds__(1024) void k_scan(const int* __restrict__ deg, int* __restrict__ rowptr) {
    __shared__ int wsum[16];
    __shared__ int s_carry;
    int tid = threadIdx.x;
    int lane = tid & 63, wv = tid >> 6;
    if (tid == 0) s_carry = 0;
    __syncthreads();
    for (int base = 0; base < NN; base += 1024) {
        int i = base + tid;
        int v = (i < NN) ? deg[i] : 0;
        int x = v;
        #pragma unroll
        for (int off = 1; off < 64; off <<= 1) {
            int t = __shfl_up(x, off);
            if (lane >= off) x += t;
        }
        if (lane == 63) wsum[wv] = x;
        __syncthreads();
        if (tid < 16) {
            int y = wsum[tid];
            #pragma unroll
            for (int off = 1; off < 16; off <<= 1) {
                int t = __shfl_up(y, off);
                if (tid >= off) y += t;
            }
            wsum[tid] = y;
        }
        __syncthreads();
        int wbase = ((wv > 0) ? wsum[wv - 1] : 0) + s_carry;
        if (i < NN) rowptr[i] = wbase + x - v;
        int tot = wsum[15];
        __syncthreads();
        if (tid == 0) s_carry += tot;
    }
    __syncthreads();
    if (tid == 0) rowptr[NN] = s_carry;
}

__global__ __launch_bounds__(256) void k_scatter(const int* __restrict__ src, const int* __restrict__ dst,
                                                 const int* __restrict__ attr, const int* __restrict__ rowptr,
                                                 int* __restrict__ fill, int* __restrict__ csr) {
    int e = blockIdx.x * 256 + threadIdx.x;
    if (e < NE) {
        int d = dst[e];
        int pos = rowptr[d] + atomicAdd(&fill[d], 1);
        csr[pos] = src[e] | (attr[e] << 20);
    }
}

// amp/inv per node (degree-only, layer-invariant)
__global__ __launch_bounds__(256) void k_amp(const int* __restrict__ rowptr,
                                             float* __restrict__ amp, float* __restrict__ inv) {
    int n = blockIdx.x * 256 + threadIdx.x;
    if (n < NN) {
        int dg = rowptr[n + 1] - rowptr[n];
        float cnt = fmaxf((float)dg, 1.0f);
        float a = logf(cnt + 1.0f) * (1.0f / AMP_DENOM);
        amp[n] = a;
        inv[n] = 1.0f / a;
    }
}

// ---------------- embedding: hb bf16 (with zero k-pad) ----------------
__global__ __launch_bounds__(256) void k_h0(const int* __restrict__ x, const float* __restrict__ emb,
                                            unsigned short* __restrict__ hb) {
    int idx = blockIdx.x * 256 + threadIdx.x;
    if (idx < NN * HBW) {
        int n = idx / HBW, f = idx % HBW;
        hb[idx] = (f < FI) ? f2bf(emb[x[n] * FI + f]) : (unsigned short)0;
    }
}

// ---------------- Wp5: fragment-packed post weights [NL][NT][3][10 ks][64 lane][8 e] ----------------
__global__ __launch_bounds__(256) void k_wprep5(const float* __restrict__ post_w,
                                                unsigned short* __restrict__ Wp5) {
    int idx = blockIdx.x * 256 + threadIdx.x;
    if (idx >= NL * NT * 3 * 10 * 512) return;
    int e = idx & 7;
    int lane = (idx >> 3) & 63;
    int ks = (idx >> 9) % 10;
    int s = (idx / 5120) % 3;
    int t = (idx / 15360) % NT;
    int l = idx / 76800;
    int lr = lane & 15, lq = lane >> 4;
    int kk = ks * 32 + lq * 8 + e;
    float val = 0.0f;
    if (kk < 304 && lr < 15) {
        int stat = kk / 76, of = kk - stat * 76;
        if (of < 75)
            val = post_w[((size_t)(l * NT + t) * 975 + 75 + s * 300 + stat * 75 + of) * 15 + lr];
    }
    Wp5[idx] = f2bf(val);
}

// ---------------- Wp2f: fragment-packed preab weights [NL][52 nt][3 ks][64 lane][8 e] ----------------
__global__ __launch_bounds__(256) void k_wprep2f(const float* __restrict__ pre_w,
                                                 const float* __restrict__ post_w,
                                                 unsigned short* __restrict__ Wp2f) {
    int idx = blockIdx.x * 256 + threadIdx.x;
    if (idx >= NL * 52 * 3 * 512) return;
    int e = idx & 7;
    int lane = (idx >> 3) & 63;
    int ks = (idx >> 9) % 3;
    int nt = (idx / 1536) % 52;
    int l = idx / (1536 * 52);
    int lr = lane & 15, lq = lane >> 4;
    int j = nt * 16 + lr;
    int k = ks * 32 + lq * 8 + e;
    float val = 0.0f;
    if (k < 75 && j < 825) {
        if (j < 375) {
            int t = j / 75, o = j % 75;
            val = pre_w[((size_t)(l * NT + t) * 225 + k) * FI + o];
        } else if (j < 750) {
            int jm = j - 375;
            int t = jm / 75, o = jm % 75;
            val = pre_w[((size_t)(l * NT + t) * 225 + 75 + k) * FI + o];
        } else {
            int c = j - 750;
            int t = c / 15, o = c % 15;
            val = post_w[((size_t)(l * NT + t) * 975 + k) * 15 + o];
        }
    }
    Wp2f[idx] = f2bf(val);
}

// ---------------- linTp: fragment-packed lin weights [NL][5 nt][3 ks][64 lane][8 e] ----------------
__global__ __launch_bounds__(256) void k_wprep4(const float* __restrict__ lin_w,
                                                unsigned short* __restrict__ linTp) {
    int idx = blockIdx.x * 256 + threadIdx.x;
    if (idx >= NL * 5 * 3 * 512) return;
    int e = idx & 7;
    int lane = (idx >> 3) & 63;
    int ks = (idx >> 9) % 3;
    int nt = (idx / 1536) % 5;
    int l = idx / 7680;
    int lr = lane & 15, lq = lane >> 4;
    int c = nt * 16 + lr;
    int k = ks * 32 + lq * 8 + e;
    float v = 0.0f;
    if (k < 75 && c < 75) v = lin_w[(size_t)l * 5625 + k * 75 + c];
    linTp[idx] = f2bf(v);
}

// ---------------- edge-type tables for ALL layers ----------------
__global__ __launch_bounds__(384) void k_tbl4(const float* __restrict__ edge_emb, const float* __restrict__ enc_w,
                                              const float* __restrict__ enc_b, const float* __restrict__ pre_w,
                                              const float* __restrict__ pre_b, float* __restrict__ tbl4) {
    __shared__ float e4[4][FI];
    int l = blockIdx.x;
    int tid = threadIdx.x;
    float* tbl = tbl4 + l * 1500;
    if (tid < 300) {
        int a = tid / FI, f = tid % FI;
        float acc = enc_b[l * FI + f];
        for (int k = 0; k < 50; k++)
            acc += edge_emb[a * 50 + k] * enc_w[(l * 50 + k) * FI + f];
        e4[a][f] = acc;
    }
    __syncthreads();
    for (int idx = tid; idx < 4 * 375; idx += 384) {
        int a = idx / 375, c = idx % 375;
        int t = c / FI, o = c % FI;
        const float* wp = pre_w + ((size_t)(l * NT + t) * 225 + 150) * FI + o;
        float acc = pre_b[(l * NT + t) * FI + o];
        for (int f = 0; f < FI; f++)
            acc += e4[a][f] * wp[f * FI];
        tbl[idx] = acc;
    }
}

// ---------------- BN + ReLU: z -> hb bf16 (vectorized, 8 cols/thread) ----------------
__global__ __launch_bounds__(256) void k_bnh(const float* __restrict__ z, const float* __restrict__ bnsum,
                                             const float* __restrict__ bng, const float* __restrict__ bnb,
                                             unsigned short* __restrict__ hb) {
    __shared__ float s_sc[76], s_sh[76];
    int tid = threadIdx.x;
    if (tid < 76) {
        if (tid < 75) {
            float mu = bnsum[tid] * (1.0f / NN);
            float msq = bnsum[76 + tid] * (1.0f / NN);
            float var = msq - mu * mu;
            float sc = rsqrtf(var + 1e-5f) * bng[tid];
            s_sc[tid] = sc;
            s_sh[tid] = bnb[tid] - mu * sc;
        } else {
            s_sc[tid] = 0.0f;
            s_sh[tid] = 0.0f;
        }
    }
    __syncthreads();
    int idx = blockIdx.x * 256 + tid;
    if (idx < NN * 12) {
        int n = idx / 12, q = idx % 12;
        int c0 = q * 8;
        unsigned short r[8];
        if (c0 < 72) {
            float4 a = *(const float4*)&z[(size_t)n * ZW + c0];
            float4 b = *(const float4*)&z[(size_t)n * ZW + c0 + 4];
            float vv[8] = {a.x, a.y, a.z, a.w, b.x, b.y, b.z, b.w};
            #pragma unroll
            for (int j = 0; j < 8; j++)
                r[j] = f2bf(fmaxf(vv[j] * s_sc[c0 + j] + s_sh[c0 + j], 0.0f));
        } else if (c0 == 72) {
            float4 a = *(const float4*)&z[(size_t)n * ZW + 72];
            float vv[4] = {a.x, a.y, a.z, a.w};
            #pragma unroll
            for (int j = 0; j < 8; j++)
                r[j] = (j < 3) ? f2bf(fmaxf(vv[j] * s_sc[72 + j] + s_sh[72 + j], 0.0f))
                               : (unsigned short)0;
        } else {
            #pragma unroll
            for (int j = 0; j < 8; j++) r[j] = 0;
        }
        *(uint4*)&hb[(size_t)n * HBW + c0] = *(uint4*)r;
    }
}

// ---------------- MFMA ABH = hb @ Wcat^T : A in LDS, B fragments from global ----------------
__global__ __launch_bounds__(256) void k_preab(const unsigned short* __restrict__ hb,
                                               const unsigned short* __restrict__ Wp2f,
                                               int l, __hip_bfloat16* __restrict__ ABH) {
    __shared__ __align__(16) unsigned short sA[128 * 104];
    int tid = threadIdx.x;
    int m0 = blockIdx.x * 128;
    int jt0 = blockIdx.y * 13;   // 13 n-tiles of 16 cols each

    const uint4* hsrc = (const uint4*)hb;
    for (int c = tid; c < 128 * 12; c += 256) {
        int r = c / 12, q = c % 12;
        int n = m0 + r;
        uint4 v = make_uint4(0, 0, 0, 0);
        if (n < NN) v = hsrc[(size_t)n * 12 + q];
        *(uint4*)&sA[r * 104 + q * 8] = v;
    }
    __syncthreads();

    int w = tid >> 6, lane = tid & 63;
    int mw = w * 32;
    int lr = lane & 15, lq = lane >> 4;

    bf16x8 af[2][3];
    #pragma unroll
    for (int mt = 0; mt < 2; mt++)
        #pragma unroll
        for (int ks = 0; ks < 3; ks++)
            af[mt][ks] = *(const bf16x8*)&sA[(mw + mt * 16 + lr) * 104 + ks * 32 + lq * 8];

    f32x4 acc[13][2];
    #pragma unroll
    for (int nt = 0; nt < 13; nt++)
        #pragma unroll
        for (int mt = 0; mt < 2; mt++)
            acc[nt][mt] = (f32x4){0.0f, 0.0f, 0.0f, 0.0f};

    const unsigned short* wp = Wp2f + ((size_t)l * 52 + jt0) * 3 * 512;
    // swapped operands: output col(lane&15) = node (af rows), VGPR row (lq*4+r) = j (weight rows)
    #pragma unroll
    for (int nt = 0; nt < 13; nt++) {
        #pragma unroll
        for (int ks = 0; ks < 3; ks++) {
            bf16x8 bf = *(const bf16x8*)&wp[(nt * 3 + ks) * 512 + lane * 8];
            acc[nt][0] = __builtin_amdgcn_mfma_f32_16x16x32_bf16(bf, af[0][ks], acc[nt][0], 0, 0, 0);
            acc[nt][1] = __builtin_amdgcn_mfma_f32_16x16x32_bf16(bf, af[1][ks], acc[nt][1], 0, 0, 0);
        }
    }

    unsigned short* abo = (unsigned short*)ABH;
    int j0 = jt0 * 16;
    #pragma unroll
    for (int mt = 0; mt < 2; mt++) {
        int n = m0 + mw + mt * 16 + lr;
        if (n < NN) {
            #pragma unroll
            for (int nt = 0; nt < 13; nt++) {
                int c0 = j0 + nt * 16 + lq * 4;
                ushort4 us;
                us.x = f2bf(acc[nt][mt][0]);
                us.y = f2bf(acc[nt][mt][1]);
                us.z = f2bf(acc[nt][mt][2]);
                us.w = f2bf(acc[nt][mt][3]);
                *(ushort4*)&abo[(size_t)n * ABW + c0] = us;
            }
        }
    }
}

// ---------------- gather: per-node stats -> AGG bf16 (R8-exact body) ----------------
__global__ __launch_bounds__(256) void k_gather(const __hip_bfloat16* __restrict__ ABH,
                                                const float* __restrict__ tbl,
                                                const int* __restrict__ rowptr, const int* __restrict__ csr,
                                                unsigned short* __restrict__ AGG) {
    __shared__ float s_tbl[1500];
    int tid = threadIdx.x;
    for (int i = tid; i < 1500; i += 256) s_tbl[i] = tbl[i];
    __syncthreads();

    int w = tid >> 6, l = tid & 63;
    int n = blockIdx.x * 4 + w;
    int base = rowptr[n];
    int dg = rowptr[n + 1] - base;

    float sum[6], ss[6], mn[6], mx[6];
    #pragma unroll
    for (int j = 0; j < 6; j++) { sum[j] = 0.f; ss[j] = 0.f; mn[j] = FLT_MAX; mx[j] = -FLT_MAX; }

    const unsigned short* abu = (const unsigned short*)ABH;
    int k = 0;
    for (; k + 1 < dg; k += 2) {
        int pk0 = csr[base + k], pk1 = csr[base + k + 1];
        const unsigned short* bp0 = abu + (size_t)(pk0 & 0xFFFFF) * ABW + 375;
        const unsigned short* bp1 = abu + (size_t)(pk1 & 0xFFFFF) * ABW + 375;
        const float* tp0 = s_tbl + (pk0 >> 20) * 375;
        const float* tp1 = s_tbl + (pk1 >> 20) * 375;
        #pragma unroll
        for (int j = 0; j < 6; j++) {
            int f = l + 64 * j;
            if (f < 375) {
                float v0 = bf2f(bp0[f]) + tp0[f];
                float v1 = bf2f(bp1[f]) + tp1[f];
                sum[j] += v0 + v1;
                ss[j] += v0 * v0 + v1 * v1;
                mn[j] = fminf(mn[j], fminf(v0, v1));
                mx[j] = fmaxf(mx[j], fmaxf(v0, v1));
            }
        }
    }
    if (k < dg) {
        int pk0 = csr[base + k];
        const unsigned short* bp0 = abu + (size_t)(pk0 & 0xFFFFF) * ABW + 375;
        const float* tp0 = s_tbl + (pk0 >> 20) * 375;
        #pragma unroll
        for (int j = 0; j < 6; j++) {
            int f = l + 64 * j;
            if (f < 375) {
                float v0 = bf2f(bp0[f]) + tp0[f];
                sum[j] += v0; ss[j] += v0 * v0;
                mn[j] = fminf(mn[j], v0); mx[j] = fmaxf(mx[j], v0);
            }
        }
    }

    unsigned short* out = AGG + (size_t)n * AGW;
    if (dg > 0) {
        float rc = 1.0f / (float)dg;
        const unsigned short* ap = abu + (size_t)n * ABW;
        #pragma unroll
        for (int j = 0; j < 6; j++) {
            int f = l + 64 * j;
            if (f < 375) {
                int t = f / 75, of = f - t * 75;
                int o = t * 320 + of;
                float Af = bf2f(ap[f]);
                float mean = sum[j] * rc;
                float var = ss[j] * rc - mean * mean;
                out[o]       = f2bf(Af + mean);
                out[o + 76]  = f2bf(Af + mn[j]);
                out[o + 152] = f2bf(Af + mx[j]);
                out[o + 228] = f2bf(sqrtf(fmaxf(var, 0.0f) + 1e-5f));
            }
        }
    } else {
        unsigned short zz = 0;
        unsigned short sd = f2bf(0.0031622776601683794f);  // sqrt(1e-5)
        #pragma unroll
        for (int j = 0; j < 6; j++) {
            int f = l + 64 * j;
            if (f < 375) {
                int t = f / 75, of = f - t * 75;
                int o = t * 320 + of;
                out[o] = zz; out[o + 76] = zz; out[o + 152] = zz; out[o + 228] = sd;
            }
        }
    }
    // zero pads: per tower k in [304,320), and stat pads of==75
    for (int i = l; i < 80; i += 64) out[(i >> 4) * 320 + 304 + (i & 15)] = 0;
    if (l < 20) out[(l >> 2) * 320 + (l & 3) * 76 + 75] = 0;
}

// ---------------- post: wave = (16-node tile, tower-group) ----------------
#define LOAD_A(buf, t)                                                        \
    {                                                                         \
        _Pragma("unroll")                                                     \
        for (int ks = 0; ks < 10; ks++)                                       \
            buf[ks] = *(const bf16x8*)&ap[(t) * 320 + ks * 32 + lq * 8];      \
    }

#define DO_TOWER(t, buf)                                                               \
    {                                                                                  \
        const unsigned short* wp = Wp5 + (size_t)(l * NT + (t)) * 3 * 10 * 512;        \
        f32x4 ac0 = {0, 0, 0, 0}, ac1 = {0, 0, 0, 0}, ac2 = {0, 0, 0, 0};              \
        _Pragma("unroll")                                                              \
        for (int ks = 0; ks < 10; ks++) {                                              \
            bf16x8 b0 = *(const bf16x8*)&wp[(0 * 10 + ks) * 512 + lane * 8];           \
            bf16x8 b1 = *(const bf16x8*)&wp[(1 * 10 + ks) * 512 + lane * 8];           \
            bf16x8 b2 = *(const bf16x8*)&wp[(2 * 10 + ks) * 512 + lane * 8];           \
            ac0 = __builtin_amdgcn_mfma_f32_16x16x32_bf16(b0, buf[ks], ac0, 0, 0, 0);  \
            ac1 = __builtin_amdgcn_mfma_f32_16x16x32_bf16(b1, buf[ks], ac1, 0, 0, 0);  \
            ac2 = __builtin_amdgcn_mfma_f32_16x16x32_bf16(b2, buf[ks], ac2, 0, 0, 0);  \
        }                                                                              \
        _Pragma("unroll")                                                              \
        for (int r = 0; r < 4; r++) {                                                  \
            int f = lq * 4 + r;                                                        \
            if (f < 15) {                                                              \
                float qb = post_b[(l * NT + (t)) * 15 + f];                            \
                float y = ac0[r] + amp * ac1[r] + inv * ac2[r] + htv[t][r] + qb;       \
                s_y[(u * 16 + lr) * 104 + (t) * 15 + f] = f2bf(y);                     \
            }                                                                          \
        }                                                                              \
    }

#define LOAD_HT(t)                                                                     \
    {                                                                                  \
        _Pragma("unroll")                                                              \
        for (int r = 0; r < 4; r++) {                                                  \
            int f = lq * 4 + r;                                                        \
            int fc = (f < 15) ? f : 14;                                                \
            htv[t][r] = bf2f(abu[(size_t)mclamp * ABW + 750 + (t) * 15 + fc]);         \
        }                                                                              \
    }

#define DO_LIN(nt)                                                                     \
    {                                                                                  \
        f32x4 a2 = {0, 0, 0, 0};                                                       \
        _Pragma("unroll")                                                              \
        for (int ks = 0; ks < 3; ks++) {                                               \
            bf16x8 bb = *(const bf16x8*)&lp[((nt) * 3 + ks) * 512 + lane * 8];         \
            a2 = __builtin_amdgcn_mfma_f32_16x16x32_bf16(bb, ya[ks], a2, 0, 0, 0);     \
        }                                                                              \
        int c0 = (nt) * 16 + lq * 4;                                                   \
        float v[4], vm[4], vm2[4];                                                     \
        _Pragma("unroll")                                                              \
        for (int r = 0; r < 4; r++) {                                                  \
            int c = c0 + r;                                                            \
            v[r] = (c < 75) ? (a2[r] + lin_b[l * 75 + c]) : 0.0f;                      \
            bool ok = (c < 75) && nv;                                                  \
            vm[r] = ok ? v[r] : 0.0f;                                                  \
            vm2[r] = ok ? v[r] * v[r] : 0.0f;                                          \
        }                                                                              \
        if (nv) {                                                                      \
            if (c0 + 3 < 75) {                                                         \
                float4 st = make_float4(v[0], v[1], v[2], v[3]);                       \
                *(float4*)&z[(size_t)mynode * ZW + c0] = st;                           \
            } else {                                                                   \
                _Pragma("unroll")                                                      \
                for (int r = 0; r < 4; r++)                                            \
                    if (c0 + r < 75) z[(size_t)mynode * ZW + c0 + r] = v[r];           \
            }                                                                          \
        }                                                                              \
        _Pragma("unroll")                                                              \
        for (int r = 0; r < 4; r++) {                                                  \
            _Pragma("unroll")                                                          \
            for (int off = 1; off < 16; off <<= 1) {                                   \
                vm[r] += __shfl_xor(vm[r], off);                                       \
                vm2[r] += __shfl_xor(vm2[r], off);                                     \
            }                                                                          \
        }                                                                              \
        if (lr == 0) {                                                                 \
            _Pragma("unroll")                                                          \
            for (int r = 0; r < 4; r++) {                                              \
                int c = c0 + r;                                                        \
                if (c < 75) {                                                          \
                    atomicAdd(&s_bn[c], vm[r]);                                        \
                    atomicAdd(&s_bn[76 + c], vm2[r]);                                  \
                }                                                                      \
            }                                                                          \
        }                                                                              \
    }

__global__ __launch_bounds__(256) void k_post(const __hip_bfloat16* __restrict__ ABH,
                                              const unsigned short* __restrict__ AGG,
                                              const unsigned short* __restrict__ Wp5,
                                              const unsigned short* __restrict__ linTp,
                                              const float* __restrict__ amp_a, const float* __restrict__ inv_a,
                                              const float* __restrict__ post_b, const float* __restrict__ lin_b,
                                              int l, float* __restrict__ z, float* __restrict__ bnsum) {
    __shared__ __align__(16) unsigned short s_y[32 * 104];   // 6656 B (cols 75..103 zero)
    __shared__ float s_bn[152];

    int tid = threadIdx.x;
    int n0 = blockIdx.x * 32;
    int w = tid >> 6, lane = tid & 63;
    int u = w >> 1, g = w & 1;       // tile u in {0,1}, tower-group g
    int lr = lane & 15, lq = lane >> 4;

    if (tid < 152) s_bn[tid] = 0.0f;
    for (int i = tid; i < 32 * 29; i += 256) {
        int r = i / 29, c = 75 + i % 29;
        s_y[r * 104 + c] = 0;
    }

    const unsigned short* abu = (const unsigned short*)ABH;
    int mynode = n0 + u * 16 + lr;
    bool nv = (mynode < NN);
    int mclamp = nv ? mynode : (NN - 1);
    float amp = amp_a[mclamp], inv = inv_a[mclamp];
    const unsigned short* ap = AGG + (size_t)mclamp * AGW;

    bf16x8 aA[10], aB[10];
    float htv[5][4];

    if (g == 0) {   // towers 0,1,2
        LOAD_A(aA, 0)
        LOAD_HT(0) LOAD_HT(1) LOAD_HT(2)
        LOAD_A(aB, 1)
        DO_TOWER(0, aA)
        LOAD_A(aA, 2)
        DO_TOWER(1, aB)
        DO_TOWER(2, aA)
    } else {        // towers 3,4
        LOAD_A(aA, 3)
        LOAD_HT(3) LOAD_HT(4)
        LOAD_A(aB, 4)
        DO_TOWER(3, aA)
        DO_TOWER(4, aB)
    }
    __syncthreads();

    // lin via MFMA: z = y[32,96] @ linT^T; wave (u,g): g=0 -> col-tiles 0,1,2; g=1 -> 3,4
    const unsigned short* lp = linTp + (size_t)l * 5 * 3 * 512;
    bf16x8 ya[3];
    #pragma unroll
    for (int ks = 0; ks < 3; ks++)
        ya[ks] = *(const bf16x8*)&s_y[(u * 16 + lr) * 104 + ks * 32 + lq * 8];

    if (g == 0) {
        DO_LIN(0) DO_LIN(1) DO_LIN(2)
    } else {
        DO_LIN(3) DO_LIN(4)
    }
    __syncthreads();
    if (tid < 75) {
        atomicAdd(&bnsum[tid], s_bn[tid]);
        atomicAdd(&bnsum[76 + tid], s_bn[76 + tid]);
    }
}

// ---------------- pooling (BN fused) + MLP ----------------
__global__ __launch_bounds__(256) void k_pool(const float* __restrict__ z, const float* __restrict__ bnsum3,
                                              const float* __restrict__ bng, const float* __restrict__ bnb,
                                              const int* __restrict__ batch, float* __restrict__ hg) {
    __shared__ float s_sc[75], s_sh[75];
    int tid = threadIdx.x;
    if (tid < 75) {
        float mu = bnsum3[tid] * (1.0f / NN);
        float msq = bnsum3[76 + tid] * (1.0f / NN);
        float var = msq - mu * mu;
        float sc = rsqrtf(var + 1e-5f) * bng[tid];
        s_sc[tid] = sc;
        s_sh[tid] = bnb[tid] - mu * sc;
    }
    __syncthreads();
    int idx = blockIdx.x * 256 + tid;
    if (idx < NN * 75) {
        int n = idx / 75, f = idx % 75;
        float v = fmaxf(z[(size_t)n * ZW + f] * s_sc[f] + s_sh[f], 0.0f);
        atomicAdd(&hg[batch[n] * 75 + f], v);
    }
}

__global__ __launch_bounds__(64) void k_mlp(const float* __restrict__ hg,
                                            const float* __restrict__ w1, const float* __restrict__ b1,
                                            const float* __restrict__ w2, const float* __restrict__ b2,
                                            const float* __restrict__ w3, const float* __restrict__ b3,
                                            float* __restrict__ out) {
    __shared__ float zin[75], z1[50], z2[25];
    int g = blockIdx.x, tid = threadIdx.x;
    for (int k = tid; k < 75; k += 64) zin[k] = hg[g * 75 + k];
    __syncthreads();
    if (tid < 50) {
        float acc = b1[tid];
        for (int k = 0; k < 75; k++) acc += zin[k] * w1[k * 50 + tid];
        z1[tid] = fmaxf(acc, 0.0f);
    }
    __syncthreads();
    if (tid < 25) {
        float acc = b2[tid];
        for (int k = 0; k < 50; k++) acc += z1[k] * w2[k * 25 + tid];
        z2[tid] = fmaxf(acc, 0.0f);
    }
    __syncthreads();
    if (tid == 0) {
        float acc = b3[0];
        for (int k = 0; k < 25; k++) acc += z2[k] * w3[k];
        out[g] = acc;
    }
}

extern "C" void kernel_launch(void* const* d_in, const int* in_sizes, int n_in,
                              void* d_out, int out_size, void* d_ws, size_t ws_size,
                              hipStream_t stream) {
    const int* x        = (const int*)d_in[0];
    const int* ei       = (const int*)d_in[1];
    const int* eattr    = (const int*)d_in[2];
    const int* batch    = (const int*)d_in[3];
    const float* node_emb = (const float*)d_in[4];
    const float* edge_emb = (const float*)d_in[5];
    const float* enc_w  = (const float*)d_in[6];
    const float* enc_b  = (const float*)d_in[7];
    const float* pre_w  = (const float*)d_in[8];
    const float* pre_b  = (const float*)d_in[9];
    const float* post_w = (const float*)d_in[10];
    const float* post_b = (const float*)d_in[11];
    const float* lin_w  = (const float*)d_in[12];
    const float* lin_b  = (const float*)d_in[13];
    const float* bn_g   = (const float*)d_in[14];
    const float* bn_b   = (const float*)d_in[15];
    const float* w1     = (const float*)d_in[16];
    const float* b1     = (const float*)d_in[17];
    const float* w2     = (const float*)d_in[18];
    const float* b2     = (const float*)d_in[19];
    const float* w3     = (const float*)d_in[20];
    const float* b3     = (const float*)d_in[21];

    char* p = (char*)d_ws;
    auto carve = [&](size_t bytes) -> char* {
        char* r = p;
        p += ((bytes + 255) & ~(size_t)255);
        return r;
    };
    __hip_bfloat16* ABH = (__hip_bfloat16*)carve((size_t)NN * ABW * 2);
    unsigned short* AGG = (unsigned short*)carve((size_t)NN * AGW * 2);
    float* z     = (float*)carve((size_t)NN * ZW * 4);
    unsigned short* hb = (unsigned short*)carve((size_t)NN * HBW * 2);
    unsigned short* Wp2f  = (unsigned short*)carve((size_t)NL * 52 * 3 * 512 * 2);
    unsigned short* Wp5   = (unsigned short*)carve((size_t)NL * NT * 3 * 10 * 512 * 2);
    unsigned short* linTp = (unsigned short*)carve((size_t)NL * 5 * 3 * 512 * 2);
    float* tbl4  = (float*)carve((size_t)NL * 1500 * 4);
    int* deg     = (int*)carve(NN * 4);
    int* rowptr  = (int*)carve((NN + 1) * 4);
    int* fill    = (int*)carve(NN * 4);
    int* csr     = (int*)carve(NE * 4);
    float* bnsum = (float*)carve((size_t)NL * 152 * 4);
    float* amp_a = (float*)carve(NN * 4);
    float* inv_a = (float*)carve(NN * 4);
    float* hg    = (float*)carve((size_t)NG * 75 * 4);

    hipMemsetAsync(deg, 0, NN * 4, stream);
    hipMemsetAsync(fill, 0, NN * 4, stream);
    hipMemsetAsync(hg, 0, (size_t)NG * 75 * 4, stream);
    hipMemsetAsync(bnsum, 0, (size_t)NL * 152 * 4, stream);

    k_deg<<<(NE + 255) / 256, 256, 0, stream>>>(ei + NE, deg);
    k_scan<<<1, 1024, 0, stream>>>(deg, rowptr);
    k_scatter<<<(NE + 255) / 256, 256, 0, stream>>>(ei, ei + NE, eattr, rowptr, fill, csr);
    k_amp<<<(NN + 255) / 256, 256, 0, stream>>>(rowptr, amp_a, inv_a);
    k_h0<<<(NN * HBW + 255) / 256, 256, 0, stream>>>(x, node_emb, hb);
    k_wprep5<<<(NL * NT * 3 * 10 * 512 + 255) / 256, 256, 0, stream>>>(post_w, Wp5);
    k_wprep2f<<<(NL * 52 * 3 * 512 + 255) / 256, 256, 0, stream>>>(pre_w, post_w, Wp2f);
    k_wprep4<<<(NL * 5 * 3 * 512 + 255) / 256, 256, 0, stream>>>(lin_w, linTp);
    k_tbl4<<<NL, 384, 0, stream>>>(edge_emb, enc_w, enc_b, pre_w, pre_b, tbl4);

    for (int l = 0; l < NL; l++) {
        if (l > 0)
            k_bnh<<<(NN * 12 + 255) / 256, 256, 0, stream>>>(
                z, bnsum + (l - 1) * 152, bn_g + (l - 1) * 75, bn_b + (l - 1) * 75, hb);
        k_preab<<<dim3((NN + 127) / 128, 4), 256, 0, stream>>>(hb, Wp2f, l, ABH);
        k_gather<<<NN / 4, 256, 0, stream>>>(ABH, tbl4 + l * 1500, rowptr, csr, AGG);
        k_post<<<(NN + 31) / 32, 256, 0, stream>>>(ABH, AGG, Wp5, linTp, amp_a, inv_a,
                                                   post_b, lin_b, l, z, bnsum + l * 152);
    }

    k_pool<<<(NN * 75 + 255) / 256, 256, 0, stream>>>(z, bnsum + 3 * 152, bn_g + 3 * 75, bn_b + 3 * 75,
                                                      batch, hg);
    k_mlp<<<NG, 64, 0, stream>>>(hg, w1, b1, w2, b2, w3, b3, (float*)d_out);
}

// Round 14
// 572.566 us; speedup vs baseline: 1.0890x; 1.0890x over previous
//
#include <hip/hip_runtime.h>
#include <hip/hip_bf16.h>
#include <float.h>
#include <math.h>

#define NN 30000
#define NE 70000
#define NG 1024
#define NT 5
#define FI 75
#define NL 4

// AVG_DEG_LOG = (100*ln2 + 400*ln3 + 300*ln4 + 50*ln5)/850
#define AMP_DENOM 1.1824939264481302f

// ABH: [NN][832] bf16 : cols 0..374 = A (h@Wdst), 375..749 = B (h@Wsrc),
//                        750..824 = hterm, 825..831 pad
#define ABW 832
// AGGf: fragment-major per 16-node tile: [1875 tile][5 t][10 ks][16 lr][4 lq][8 e] bf16
//       value (node n, tower t, kk in [0,320)) at tile(n>>4), ks=kk>>5, lr=n&15, within=kk&31
#define TILES 1875
#define TILE_SH 25600     // shorts per tile = 5*10*512
// hb: [NN][96] bf16, cols 75..95 zero
#define HBW 96
// z: [NN][76] f32
#define ZW 76

typedef __attribute__((ext_vector_type(8))) short bf16x8;
typedef __attribute__((ext_vector_type(4))) float f32x4;

__device__ __forceinline__ float bf2f(unsigned short u) {
    return __uint_as_float(((unsigned int)u) << 16);
}
__device__ __forceinline__ unsigned short f2bf(float f) {
    __hip_bfloat16 h = __float2bfloat16(f);
    return *reinterpret_cast<unsigned short*>(&h);
}
__device__ __forceinline__ size_t aggf_idx(int n, int t, int kk) {
    return (size_t)(n >> 4) * TILE_SH + (size_t)((t * 10 + (kk >> 5)) * 512) + ((n & 15) << 5) + (kk & 31);
}

// ---------------- CSR build ----------------
__global__ __launch_bounds__(256) void k_deg(const int* __restrict__ dst, int* __restrict__ deg) {
    int e = blockIdx.x * 256 + threadIdx.x;
    if (e < NE) atomicAdd(&deg[dst[e]], 1);
}

__global__ __launch_bounds__(1024) void k_scan(const int* __restrict__ deg, int* __restrict__ rowptr) {
    __shared__ int wsum[16];
    __shared__ int s_carry;
    int tid = threadIdx.x;
    int lane = tid & 63, wv = tid >> 6;
    if (tid == 0) s_carry = 0;
    __syncthreads();
    for (int base = 0; base < NN; base += 1024) {
        int i = base + tid;
        int v = (i < NN) ? deg[i] : 0;
        int x = v;
        #pragma unroll
        for (int off = 1; off < 64; off <<= 1) {
            int t = __shfl_up(x, off);
            if (lane >= off) x += t;
        }
        if (lane == 63) wsum[wv] = x;
        __syncthreads();
        if (tid < 16) {
            int y = wsum[tid];
            #pragma unroll
            for (int off = 1; off < 16; off <<= 1) {
                int t = __shfl_up(y, off);
                if (tid >= off) y += t;
            }
            wsum[tid] = y;
        }
        __syncthreads();
        int wbase = ((wv > 0) ? wsum[wv - 1] : 0) + s_carry;
        if (i < NN) rowptr[i] = wbase + x - v;
        int tot = wsum[15];
        __syncthreads();
        if (tid == 0) s_carry += tot;
    }
    __syncthreads();
    if (tid == 0) rowptr[NN] = s_carry;
}

__global__ __launch_bounds__(256) void k_scatter(const int* __restrict__ src, const int* __restrict__ dst,
                                                 const int* __restrict__ attr, const int* __restrict__ rowptr,
                                                 int* __restrict__ fill, int* __restrict__ csr) {
    int e = blockIdx.x * 256 + threadIdx.x;
    if (e < NE) {
        int d = dst[e];
        int pos = rowptr[d] + atomicAdd(&fill[d], 1);
        csr[pos] = src[e] | (attr[e] << 20);
    }
}

// amp/inv per node (degree-only, layer-invariant)
__global__ __launch_bounds__(256) void k_amp(const int* __restrict__ rowptr,
                                             float* __restrict__ amp, float* __restrict__ inv) {
    int n = blockIdx.x * 256 + threadIdx.x;
    if (n < NN) {
        int dg = rowptr[n + 1] - rowptr[n];
        float cnt = fmaxf((float)dg, 1.0f);
        float a = logf(cnt + 1.0f) * (1.0f / AMP_DENOM);
        amp[n] = a;
        inv[n] = 1.0f / a;
    }
}

// ---------------- embedding: hb bf16 (with zero k-pad) ----------------
__global__ __launch_bounds__(256) void k_h0(const int* __restrict__ x, const float* __restrict__ emb,
                                            unsigned short* __restrict__ hb) {
    int idx = blockIdx.x * 256 + threadIdx.x;
    if (idx < NN * HBW) {
        int n = idx / HBW, f = idx % HBW;
        hb[idx] = (f < FI) ? f2bf(emb[x[n] * FI + f]) : (unsigned short)0;
    }
}

// ---------------- Wp5: fragment-packed post weights [NL][NT][3][10 ks][64 lane][8 e] ----------------
__global__ __launch_bounds__(256) void k_wprep5(const float* __restrict__ post_w,
                                                unsigned short* __restrict__ Wp5) {
    int idx = blockIdx.x * 256 + threadIdx.x;
    if (idx >= NL * NT * 3 * 10 * 512) return;
    int e = idx & 7;
    int lane = (idx >> 3) & 63;
    int ks = (idx >> 9) % 10;
    int s = (idx / 5120) % 3;
    int t = (idx / 15360) % NT;
    int l = idx / 76800;
    int lr = lane & 15, lq = lane >> 4;
    int kk = ks * 32 + lq * 8 + e;
    float val = 0.0f;
    if (kk < 304 && lr < 15) {
        int stat = kk / 76, of = kk - stat * 76;
        if (of < 75)
            val = post_w[((size_t)(l * NT + t) * 975 + 75 + s * 300 + stat * 75 + of) * 15 + lr];
    }
    Wp5[idx] = f2bf(val);
}

// ---------------- Wp2f: fragment-packed preab weights [NL][52 nt][3 ks][64 lane][8 e] ----------------
__global__ __launch_bounds__(256) void k_wprep2f(const float* __restrict__ pre_w,
                                                 const float* __restrict__ post_w,
                                                 unsigned short* __restrict__ Wp2f) {
    int idx = blockIdx.x * 256 + threadIdx.x;
    if (idx >= NL * 52 * 3 * 512) return;
    int e = idx & 7;
    int lane = (idx >> 3) & 63;
    int ks = (idx >> 9) % 3;
    int nt = (idx / 1536) % 52;
    int l = idx / (1536 * 52);
    int lr = lane & 15, lq = lane >> 4;
    int j = nt * 16 + lr;
    int k = ks * 32 + lq * 8 + e;
    float val = 0.0f;
    if (k < 75 && j < 825) {
        if (j < 375) {
            int t = j / 75, o = j % 75;
            val = pre_w[((size_t)(l * NT + t) * 225 + k) * FI + o];
        } else if (j < 750) {
            int jm = j - 375;
            int t = jm / 75, o = jm % 75;
            val = pre_w[((size_t)(l * NT + t) * 225 + 75 + k) * FI + o];
        } else {
            int c = j - 750;
            int t = c / 15, o = c % 15;
            val = post_w[((size_t)(l * NT + t) * 975 + k) * 15 + o];
        }
    }
    Wp2f[idx] = f2bf(val);
}

// ---------------- linTp: fragment-packed lin weights [NL][5 nt][3 ks][64 lane][8 e] ----------------
__global__ __launch_bounds__(256) void k_wprep4(const float* __restrict__ lin_w,
                                                unsigned short* __restrict__ linTp) {
    int idx = blockIdx.x * 256 + threadIdx.x;
    if (idx >= NL * 5 * 3 * 512) return;
    int e = idx & 7;
    int lane = (idx >> 3) & 63;
    int ks = (idx >> 9) % 3;
    int nt = (idx / 1536) % 5;
    int l = idx / 7680;
    int lr = lane & 15, lq = lane >> 4;
    int c = nt * 16 + lr;
    int k = ks * 32 + lq * 8 + e;
    float v = 0.0f;
    if (k < 75 && c < 75) v = lin_w[(size_t)l * 5625 + k * 75 + c];
    linTp[idx] = f2bf(v);
}

// ---------------- edge-type tables for ALL layers ----------------
__global__ __launch_bounds__(384) void k_tbl4(const float* __restrict__ edge_emb, const float* __restrict__ enc_w,
                                              const float* __restrict__ enc_b, const float* __restrict__ pre_w,
                                              const float* __restrict__ pre_b, float* __restrict__ tbl4) {
    __shared__ float e4[4][FI];
    int l = blockIdx.x;
    int tid = threadIdx.x;
    float* tbl = tbl4 + l * 1500;
    if (tid < 300) {
        int a = tid / FI, f = tid % FI;
        float acc = enc_b[l * FI + f];
        for (int k = 0; k < 50; k++)
            acc += edge_emb[a * 50 + k] * enc_w[(l * 50 + k) * FI + f];
        e4[a][f] = acc;
    }
    __syncthreads();
    for (int idx = tid; idx < 4 * 375; idx += 384) {
        int a = idx / 375, c = idx % 375;
        int t = c / FI, o = c % FI;
        const float* wp = pre_w + ((size_t)(l * NT + t) * 225 + 150) * FI + o;
        float acc = pre_b[(l * NT + t) * FI + o];
        for (int f = 0; f < FI; f++)
            acc += e4[a][f] * wp[f * FI];
        tbl[idx] = acc;
    }
}

// ---------------- BN + ReLU: z -> hb bf16 (vectorized, 8 cols/thread) ----------------
__global__ __launch_bounds__(256) void k_bnh(const float* __restrict__ z, const float* __restrict__ bnsum,
                                             const float* __restrict__ bng, const float* __restrict__ bnb,
                                             unsigned short* __restrict__ hb) {
    __shared__ float s_sc[76], s_sh[76];
    int tid = threadIdx.x;
    if (tid < 76) {
        if (tid < 75) {
            float mu = bnsum[tid] * (1.0f / NN);
            float msq = bnsum[76 + tid] * (1.0f / NN);
            float var = msq - mu * mu;
            float sc = rsqrtf(var + 1e-5f) * bng[tid];
            s_sc[tid] = sc;
            s_sh[tid] = bnb[tid] - mu * sc;
        } else {
            s_sc[tid] = 0.0f;
            s_sh[tid] = 0.0f;
        }
    }
    __syncthreads();
    int idx = blockIdx.x * 256 + tid;
    if (idx < NN * 12) {
        int n = idx / 12, q = idx % 12;
        int c0 = q * 8;
        unsigned short r[8];
        if (c0 < 72) {
            float4 a = *(const float4*)&z[(size_t)n * ZW + c0];
            float4 b = *(const float4*)&z[(size_t)n * ZW + c0 + 4];
            float vv[8] = {a.x, a.y, a.z, a.w, b.x, b.y, b.z, b.w};
            #pragma unroll
            for (int j = 0; j < 8; j++)
                r[j] = f2bf(fmaxf(vv[j] * s_sc[c0 + j] + s_sh[c0 + j], 0.0f));
        } else if (c0 == 72) {
            float4 a = *(const float4*)&z[(size_t)n * ZW + 72];
            float vv[4] = {a.x, a.y, a.z, a.w};
            #pragma unroll
            for (int j = 0; j < 8; j++)
                r[j] = (j < 3) ? f2bf(fmaxf(vv[j] * s_sc[72 + j] + s_sh[72 + j], 0.0f))
                               : (unsigned short)0;
        } else {
            #pragma unroll
            for (int j = 0; j < 8; j++) r[j] = 0;
        }
        *(uint4*)&hb[(size_t)n * HBW + c0] = *(uint4*)r;
    }
}

// ---------------- MFMA ABH = hb @ Wcat^T : A in LDS, B fragments from global ----------------
__global__ __launch_bounds__(256) void k_preab(const unsigned short* __restrict__ hb,
                                               const unsigned short* __restrict__ Wp2f,
                                               int l, __hip_bfloat16* __restrict__ ABH) {
    __shared__ __align__(16) unsigned short sA[128 * 104];
    int tid = threadIdx.x;
    int m0 = blockIdx.x * 128;
    int jt0 = blockIdx.y * 13;   // 13 n-tiles of 16 cols each

    const uint4* hsrc = (const uint4*)hb;
    for (int c = tid; c < 128 * 12; c += 256) {
        int r = c / 12, q = c % 12;
        int n = m0 + r;
        uint4 v = make_uint4(0, 0, 0, 0);
        if (n < NN) v = hsrc[(size_t)n * 12 + q];
        *(uint4*)&sA[r * 104 + q * 8] = v;
    }
    __syncthreads();

    int w = tid >> 6, lane = tid & 63;
    int mw = w * 32;
    int lr = lane & 15, lq = lane >> 4;

    bf16x8 af[2][3];
    #pragma unroll
    for (int mt = 0; mt < 2; mt++)
        #pragma unroll
        for (int ks = 0; ks < 3; ks++)
            af[mt][ks] = *(const bf16x8*)&sA[(mw + mt * 16 + lr) * 104 + ks * 32 + lq * 8];

    f32x4 acc[13][2];
    #pragma unroll
    for (int nt = 0; nt < 13; nt++)
        #pragma unroll
        for (int mt = 0; mt < 2; mt++)
            acc[nt][mt] = (f32x4){0.0f, 0.0f, 0.0f, 0.0f};

    const unsigned short* wp = Wp2f + ((size_t)l * 52 + jt0) * 3 * 512;
    // swapped operands: output col(lane&15) = node (af rows), VGPR row (lq*4+r) = j (weight rows)
    #pragma unroll
    for (int nt = 0; nt < 13; nt++) {
        #pragma unroll
        for (int ks = 0; ks < 3; ks++) {
            bf16x8 bf = *(const bf16x8*)&wp[(nt * 3 + ks) * 512 + lane * 8];
            acc[nt][0] = __builtin_amdgcn_mfma_f32_16x16x32_bf16(bf, af[0][ks], acc[nt][0], 0, 0, 0);
            acc[nt][1] = __builtin_amdgcn_mfma_f32_16x16x32_bf16(bf, af[1][ks], acc[nt][1], 0, 0, 0);
        }
    }

    unsigned short* abo = (unsigned short*)ABH;
    int j0 = jt0 * 16;
    #pragma unroll
    for (int mt = 0; mt < 2; mt++) {
        int n = m0 + mw + mt * 16 + lr;
        if (n < NN) {
            #pragma unroll
            for (int nt = 0; nt < 13; nt++) {
                int c0 = j0 + nt * 16 + lq * 4;
                ushort4 us;
                us.x = f2bf(acc[nt][mt][0]);
                us.y = f2bf(acc[nt][mt][1]);
                us.z = f2bf(acc[nt][mt][2]);
                us.w = f2bf(acc[nt][mt][3]);
                *(ushort4*)&abo[(size_t)n * ABW + c0] = us;
            }
        }
    }
}

// ---------------- gather: per-node stats -> AGGf (fragment-major tiles) ----------------
__global__ __launch_bounds__(256) void k_gather(const __hip_bfloat16* __restrict__ ABH,
                                                const float* __restrict__ tbl,
                                                const int* __restrict__ rowptr, const int* __restrict__ csr,
                                                unsigned short* __restrict__ AGG) {
    __shared__ float s_tbl[1500];
    int tid = threadIdx.x;
    for (int i = tid; i < 1500; i += 256) s_tbl[i] = tbl[i];
    __syncthreads();

    int w = tid >> 6, l = tid & 63;
    int n = blockIdx.x * 4 + w;
    int base = rowptr[n];
    int dg = rowptr[n + 1] - base;

    float sum[6], ss[6], mn[6], mx[6];
    #pragma unroll
    for (int j = 0; j < 6; j++) { sum[j] = 0.f; ss[j] = 0.f; mn[j] = FLT_MAX; mx[j] = -FLT_MAX; }

    const unsigned short* abu = (const unsigned short*)ABH;
    int k = 0;
    for (; k + 1 < dg; k += 2) {
        int pk0 = csr[base + k], pk1 = csr[base + k + 1];
        const unsigned short* bp0 = abu + (size_t)(pk0 & 0xFFFFF) * ABW + 375;
        const unsigned short* bp1 = abu + (size_t)(pk1 & 0xFFFFF) * ABW + 375;
        const float* tp0 = s_tbl + (pk0 >> 20) * 375;
        const float* tp1 = s_tbl + (pk1 >> 20) * 375;
        #pragma unroll
        for (int j = 0; j < 6; j++) {
            int f = l + 64 * j;
            if (f < 375) {
                float v0 = bf2f(bp0[f]) + tp0[f];
                float v1 = bf2f(bp1[f]) + tp1[f];
                sum[j] += v0 + v1;
                ss[j] += v0 * v0 + v1 * v1;
                mn[j] = fminf(mn[j], fminf(v0, v1));
                mx[j] = fmaxf(mx[j], fmaxf(v0, v1));
            }
        }
    }
    if (k < dg) {
        int pk0 = csr[base + k];
        const unsigned short* bp0 = abu + (size_t)(pk0 & 0xFFFFF) * ABW + 375;
        const float* tp0 = s_tbl + (pk0 >> 20) * 375;
        #pragma unroll
        for (int j = 0; j < 6; j++) {
            int f = l + 64 * j;
            if (f < 375) {
                float v0 = bf2f(bp0[f]) + tp0[f];
                sum[j] += v0; ss[j] += v0 * v0;
                mn[j] = fminf(mn[j], v0); mx[j] = fmaxf(mx[j], v0);
            }
        }
    }

    if (dg > 0) {
        float rc = 1.0f / (float)dg;
        const unsigned short* ap = abu + (size_t)n * ABW;
        #pragma unroll
        for (int j = 0; j < 6; j++) {
            int f = l + 64 * j;
            if (f < 375) {
                int t = f / 75, of = f - t * 75;
                float Af = bf2f(ap[f]);
                float mean = sum[j] * rc;
                float var = ss[j] * rc - mean * mean;
                AGG[aggf_idx(n, t, of)]        = f2bf(Af + mean);
                AGG[aggf_idx(n, t, 76 + of)]   = f2bf(Af + mn[j]);
                AGG[aggf_idx(n, t, 152 + of)]  = f2bf(Af + mx[j]);
                AGG[aggf_idx(n, t, 228 + of)]  = f2bf(sqrtf(fmaxf(var, 0.0f) + 1e-5f));
            }
        }
    } else {
        unsigned short zz = 0;
        unsigned short sd = f2bf(0.0031622776601683794f);  // sqrt(1e-5)
        #pragma unroll
        for (int j = 0; j < 6; j++) {
            int f = l + 64 * j;
            if (f < 375) {
                int t = f / 75, of = f - t * 75;
                AGG[aggf_idx(n, t, of)]       = zz;
                AGG[aggf_idx(n, t, 76 + of)]  = zz;
                AGG[aggf_idx(n, t, 152 + of)] = zz;
                AGG[aggf_idx(n, t, 228 + of)] = sd;
            }
        }
    }
    // zero pads: per tower kk in [304,320), and stat pads of==75 (kk = stat*76+75)
    for (int i = l; i < 80; i += 64)
        AGG[aggf_idx(n, i >> 4, 304 + (i & 15))] = 0;
    if (l < 20)
        AGG[aggf_idx(n, l >> 2, (l & 3) * 76 + 75)] = 0;
}

// ---------------- post: R8 body, fragment-major sequential A reads ----------------
__global__ __launch_bounds__(256) void k_post(const __hip_bfloat16* __restrict__ ABH,
                                              const unsigned short* __restrict__ AGG,
                                              const unsigned short* __restrict__ Wp5,
                                              const unsigned short* __restrict__ linTp,
                                              const float* __restrict__ amp_a, const float* __restrict__ inv_a,
                                              const float* __restrict__ post_b, const float* __restrict__ lin_b,
                                              int l, float* __restrict__ z, float* __restrict__ bnsum) {
    __shared__ __align__(16) unsigned short s_y[64 * 104];   // 13312 B (cols 75..103 zero)
    __shared__ float s_bn[152];

    int tid = threadIdx.x;
    int n0 = blockIdx.x * 64;
    int w = tid >> 6, lane = tid & 63;
    int lr = lane & 15, lq = lane >> 4;

    if (tid < 152) s_bn[tid] = 0.0f;
    for (int i = tid; i < 64 * 29; i += 256) {
        int r = i / 29, c = 75 + i % 29;
        s_y[r * 104 + c] = 0;
    }

    const unsigned short* abu = (const unsigned short*)ABH;
    int mynode = n0 + w * 16 + lr;
    bool nv = (mynode < NN);
    int mclamp = nv ? mynode : (NN - 1);
    float amp = amp_a[mclamp], inv = inv_a[mclamp];
    int tile = blockIdx.x * 4 + w;
    if (tile > TILES - 1) tile = TILES - 1;
    const unsigned short* ap = AGG + (size_t)tile * TILE_SH + (lr << 5) + lq * 8;

    for (int t = 0; t < NT; t++) {
        const unsigned short* wp = Wp5 + (size_t)(l * NT + t) * 3 * 10 * 512;

        f32x4 ac0 = {0, 0, 0, 0}, ac1 = {0, 0, 0, 0}, ac2 = {0, 0, 0, 0};
        #pragma unroll
        for (int ks = 0; ks < 10; ks++) {
            bf16x8 a = *(const bf16x8*)&ap[(t * 10 + ks) * 512];
            bf16x8 b0 = *(const bf16x8*)&wp[(0 * 10 + ks) * 512 + lane * 8];
            bf16x8 b1 = *(const bf16x8*)&wp[(1 * 10 + ks) * 512 + lane * 8];
            bf16x8 b2 = *(const bf16x8*)&wp[(2 * 10 + ks) * 512 + lane * 8];
            ac0 = __builtin_amdgcn_mfma_f32_16x16x32_bf16(b0, a, ac0, 0, 0, 0);
            ac1 = __builtin_amdgcn_mfma_f32_16x16x32_bf16(b1, a, ac1, 0, 0, 0);
            ac2 = __builtin_amdgcn_mfma_f32_16x16x32_bf16(b2, a, ac2, 0, 0, 0);
        }
        // combine: col(lane&15)=node lr, VGPR row(lq*4+r)=feature f
        #pragma unroll
        for (int r = 0; r < 4; r++) {
            int f = lq * 4 + r;
            if (f < 15) {
                float qb = post_b[(l * NT + t) * 15 + f];
                float ht = bf2f(abu[(size_t)mclamp * ABW + 750 + t * 15 + f]);
                float y = ac0[r] + amp * ac1[r] + inv * ac2[r] + ht + qb;
                s_y[(w * 16 + lr) * 104 + t * 15 + f] = f2bf(y);
            }
        }
    }
    __syncthreads();

    // lin via MFMA: z = y[64,96] @ linT^T (wave reads its own 16 rows)
    const unsigned short* lp = linTp + (size_t)l * 5 * 3 * 512;
    bf16x8 ya[3];
    #pragma unroll
    for (int ks = 0; ks < 3; ks++)
        ya[ks] = *(const bf16x8*)&s_y[(w * 16 + lr) * 104 + ks * 32 + lq * 8];

    #pragma unroll
    for (int nt = 0; nt < 5; nt++) {
        f32x4 a2 = {0, 0, 0, 0};
        #pragma unroll
        for (int ks = 0; ks < 3; ks++) {
            bf16x8 bb = *(const bf16x8*)&lp[(nt * 3 + ks) * 512 + lane * 8];
            a2 = __builtin_amdgcn_mfma_f32_16x16x32_bf16(bb, ya[ks], a2, 0, 0, 0);
        }
        int c0 = nt * 16 + lq * 4;
        float v[4], vm[4], vm2[4];
        #pragma unroll
        for (int r = 0; r < 4; r++) {
            int c = c0 + r;
            v[r] = (c < 75) ? (a2[r] + lin_b[l * 75 + c]) : 0.0f;
            bool ok = (c < 75) && nv;
            vm[r] = ok ? v[r] : 0.0f;
            vm2[r] = ok ? v[r] * v[r] : 0.0f;
        }
        if (nv) {
            if (c0 + 3 < 75) {
                float4 st = make_float4(v[0], v[1], v[2], v[3]);
                *(float4*)&z[(size_t)mynode * ZW + c0] = st;
            } else {
                #pragma unroll
                for (int r = 0; r < 4; r++)
                    if (c0 + r < 75) z[(size_t)mynode * ZW + c0 + r] = v[r];
            }
        }
        #pragma unroll
        for (int r = 0; r < 4; r++) {
            #pragma unroll
            for (int off = 1; off < 16; off <<= 1) {
                vm[r] += __shfl_xor(vm[r], off);
                vm2[r] += __shfl_xor(vm2[r], off);
            }
        }
        if (lr == 0) {
            #pragma unroll
            for (int r = 0; r < 4; r++) {
                int c = c0 + r;
                if (c < 75) {
                    atomicAdd(&s_bn[c], vm[r]);
                    atomicAdd(&s_bn[76 + c], vm2[r]);
                }
            }
        }
    }
    __syncthreads();
    if (tid < 75) {
        atomicAdd(&bnsum[tid], s_bn[tid]);
        atomicAdd(&bnsum[76 + tid], s_bn[76 + tid]);
    }
}

// ---------------- pooling (BN fused) + MLP ----------------
__global__ __launch_bounds__(256) void k_pool(const float* __restrict__ z, const float* __restrict__ bnsum3,
                                              const float* __restrict__ bng, const float* __restrict__ bnb,
                                              const int* __restrict__ batch, float* __restrict__ hg) {
    __shared__ float s_sc[75], s_sh[75];
    int tid = threadIdx.x;
    if (tid < 75) {
        float mu = bnsum3[tid] * (1.0f / NN);
        float msq = bnsum3[76 + tid] * (1.0f / NN);
        float var = msq - mu * mu;
        float sc = rsqrtf(var + 1e-5f) * bng[tid];
        s_sc[tid] = sc;
        s_sh[tid] = bnb[tid] - mu * sc;
    }
    __syncthreads();
    int idx = blockIdx.x * 256 + tid;
    if (idx < NN * 75) {
        int n = idx / 75, f = idx % 75;
        float v = fmaxf(z[(size_t)n * ZW + f] * s_sc[f] + s_sh[f], 0.0f);
        atomicAdd(&hg[batch[n] * 75 + f], v);
    }
}

__global__ __launch_bounds__(64) void k_mlp(const float* __restrict__ hg,
                                            const float* __restrict__ w1, const float* __restrict__ b1,
                                            const float* __restrict__ w2, const float* __restrict__ b2,
                                            const float* __restrict__ w3, const float* __restrict__ b3,
                                            float* __restrict__ out) {
    __shared__ float zin[75], z1[50], z2[25];
    int g = blockIdx.x, tid = threadIdx.x;
    for (int k = tid; k < 75; k += 64) zin[k] = hg[g * 75 + k];
    __syncthreads();
    if (tid < 50) {
        float acc = b1[tid];
        for (int k = 0; k < 75; k++) acc += zin[k] * w1[k * 50 + tid];
        z1[tid] = fmaxf(acc, 0.0f);
    }
    __syncthreads();
    if (tid < 25) {
        float acc = b2[tid];
        for (int k = 0; k < 50; k++) acc += z1[k] * w2[k * 25 + tid];
        z2[tid] = fmaxf(acc, 0.0f);
    }
    __syncthreads();
    if (tid == 0) {
        float acc = b3[0];
        for (int k = 0; k < 25; k++) acc += z2[k] * w3[k];
        out[g] = acc;
    }
}

extern "C" void kernel_launch(void* const* d_in, const int* in_sizes, int n_in,
                              void* d_out, int out_size, void* d_ws, size_t ws_size,
                              hipStream_t stream) {
    const int* x        = (const int*)d_in[0];
    const int* ei       = (const int*)d_in[1];
    const int* eattr    = (const int*)d_in[2];
    const int* batch    = (const int*)d_in[3];
    const float* node_emb = (const float*)d_in[4];
    const float* edge_emb = (const float*)d_in[5];
    const float* enc_w  = (const float*)d_in[6];
    const float* enc_b  = (const float*)d_in[7];
    const float* pre_w  = (const float*)d_in[8];
    const float* pre_b  = (const float*)d_in[9];
    const float* post_w = (const float*)d_in[10];
    const float* post_b = (const float*)d_in[11];
    const float* lin_w  = (const float*)d_in[12];
    const float* lin_b  = (const float*)d_in[13];
    const float* bn_g   = (const float*)d_in[14];
    const float* bn_b   = (const float*)d_in[15];
    const float* w1     = (const float*)d_in[16];
    const float* b1     = (const float*)d_in[17];
    const float* w2     = (const float*)d_in[18];
    const float* b2     = (const float*)d_in[19];
    const float* w3     = (const float*)d_in[20];
    const float* b3     = (const float*)d_in[21];

    char* p = (char*)d_ws;
    auto carve = [&](size_t bytes) -> char* {
        char* r = p;
        p += ((bytes + 255) & ~(size_t)255);
        return r;
    };
    __hip_bfloat16* ABH = (__hip_bfloat16*)carve((size_t)NN * ABW * 2);
    unsigned short* AGG = (unsigned short*)carve((size_t)TILES * TILE_SH * 2);
    float* z     = (float*)carve((size_t)NN * ZW * 4);
    unsigned short* hb = (unsigned short*)carve((size_t)NN * HBW * 2);
    unsigned short* Wp2f  = (unsigned short*)carve((size_t)NL * 52 * 3 * 512 * 2);
    unsigned short* Wp5   = (unsigned short*)carve((size_t)NL * NT * 3 * 10 * 512 * 2);
    unsigned short* linTp = (unsigned short*)carve((size_t)NL * 5 * 3 * 512 * 2);
    float* tbl4  = (float*)carve((size_t)NL * 1500 * 4);
    int* deg     = (int*)carve(NN * 4);
    int* rowptr  = (int*)carve((NN + 1) * 4);
    int* fill    = (int*)carve(NN * 4);
    int* csr     = (int*)carve(NE * 4);
    float* bnsum = (float*)carve((size_t)NL * 152 * 4);
    float* amp_a = (float*)carve(NN * 4);
    float* inv_a = (float*)carve(NN * 4);
    float* hg    = (float*)carve((size_t)NG * 75 * 4);

    hipMemsetAsync(deg, 0, NN * 4, stream);
    hipMemsetAsync(fill, 0, NN * 4, stream);
    hipMemsetAsync(hg, 0, (size_t)NG * 75 * 4, stream);
    hipMemsetAsync(bnsum, 0, (size_t)NL * 152 * 4, stream);

    k_deg<<<(NE + 255) / 256, 256, 0, stream>>>(ei + NE, deg);
    k_scan<<<1, 1024, 0, stream>>>(deg, rowptr);
    k_scatter<<<(NE + 255) / 256, 256, 0, stream>>>(ei, ei + NE, eattr, rowptr, fill, csr);
    k_amp<<<(NN + 255) / 256, 256, 0, stream>>>(rowptr, amp_a, inv_a);
    k_h0<<<(NN * HBW + 255) / 256, 256, 0, stream>>>(x, node_emb, hb);
    k_wprep5<<<(NL * NT * 3 * 10 * 512 + 255) / 256, 256, 0, stream>>>(post_w, Wp5);
    k_wprep2f<<<(NL * 52 * 3 * 512 + 255) / 256, 256, 0, stream>>>(pre_w, post_w, Wp2f);
    k_wprep4<<<(NL * 5 * 3 * 512 + 255) / 256, 256, 0, stream>>>(lin_w, linTp);
    k_tbl4<<<NL, 384, 0, stream>>>(edge_emb, enc_w, enc_b, pre_w, pre_b, tbl4);

    for (int l = 0; l < NL; l++) {
        if (l > 0)
            k_bnh<<<(NN * 12 + 255) / 256, 256, 0, stream>>>(
                z, bnsum + (l - 1) * 152, bn_g + (l - 1) * 75, bn_b + (l - 1) * 75, hb);
        k_preab<<<dim3((NN + 127) / 128, 4), 256, 0, stream>>>(hb, Wp2f, l, ABH);
        k_gather<<<NN / 4, 256, 0, stream>>>(ABH, tbl4 + l * 1500, rowptr, csr, AGG);
        k_post<<<(NN + 63) / 64, 256, 0, stream>>>(ABH, AGG, Wp5, linTp, amp_a, inv_a,
                                                   post_b, lin_b, l, z, bnsum + l * 152);
    }

    k_pool<<<(NN * 75 + 255) / 256, 256, 0, stream>>>(z, bnsum + 3 * 152, bn_g + 3 * 75, bn_b + 3 * 75,
                                                      batch, hg);
    k_mlp<<<NG, 64, 0, stream>>>(hg, w1, b1, w2, b2, w3, b3, (float*)d_out);
}